// Round 11
// baseline (491.384 us; speedup 1.0000x reference)
//
#include <hip/hip_runtime.h>
#include <hip/hip_bf16.h>

// Network_70918499991665: 12-layer implicit-map extractor, fwd + analytic grad.
// Round 10: BARRIER-FREE single-wave blocks. Each 64-thread block owns a 64x64
// tile (4 streams x 16 pts x 64 cols), stages ONLY what it reads (A 4KB + B 4KB
// per step, 2-buf 16KB LDS) via global_load_lds, paced purely by its own
// vmcnt(8). 10 independent waves/CU, zero s_barrier. Sigmoid coupling is now
// lane/register-local (stream == m-fragment). MPAD tightened to 64-multiples.

#define NPTS 4096

typedef unsigned short u16;
typedef unsigned int   u32;
typedef __attribute__((ext_vector_type(8))) __bf16 bf16x8;
typedef __attribute__((ext_vector_type(4))) float  f32x4;

#define GLD_LDS16(g, l) __builtin_amdgcn_global_load_lds(                  \
    (const __attribute__((address_space(1))) void*)(g),                   \
    (__attribute__((address_space(3))) void*)(l), 16, 0, 0)

__device__ __forceinline__ float bf2f(u16 h) {
  return __uint_as_float(((u32)h) << 16);
}
__device__ __forceinline__ u16 f2bf(float f) {
  u32 u = __float_as_uint(f);
  u += 0x7fff + ((u >> 16) & 1);   // RNE
  return (u16)(u >> 16);
}

// softplus(100x)/100 and sigmoid(100x), numerically stable
__device__ __forceinline__ void act_sp_sg(float pre, float& sp, float& sg) {
  float z = 100.f * pre;
  float e = __expf(-fabsf(z));
  float r = 1.f / (1.f + e);
  float l = __logf(1.f + e) * 0.01f;
  if (z >= 0.f) { sg = r;       sp = pre + l; }
  else          { sg = 1.f - r; sp = l; }
}

// ---------------- weight norm: w[o] = g[o]*v[o]/||v[o]||, store bf16, pad zeros
struct LayerDesc { const float* v; const float* g; int Cin, Kpad, Cout, Mpad, woff; };
struct AllDesc { LayerDesc d[12]; };

__global__ __launch_bounds__(256)
void wnorm_kernel(AllDesc ad, u16* __restrict__ Wall) {
  const LayerDesc L = ad.d[blockIdx.y];
  const int o = blockIdx.x;
  if (o >= L.Mpad) return;
  u16* wrow = Wall + (size_t)L.woff + (size_t)o * L.Kpad;
  const int t = threadIdx.x;
  if (o >= L.Cout) {                       // zero pad rows
    for (int i = t; i < L.Kpad; i += 256) wrow[i] = 0;
    return;
  }
  const float* vrow = L.v + (size_t)o * L.Cin;
  float ss = 0.f;
  for (int i = t; i < L.Cin; i += 256) { float x = vrow[i]; ss += x * x; }
#pragma unroll
  for (int off = 32; off > 0; off >>= 1) ss += __shfl_down(ss, off);
  __shared__ float red[4];
  if ((t & 63) == 0) red[t >> 6] = ss;
  __syncthreads();
  const float scale = L.g[o] / sqrtf(red[0] + red[1] + red[2] + red[3]);
  for (int i = t; i < L.Kpad; i += 256)
    wrow[i] = (i < L.Cin) ? f2bf(vrow[i] * scale) : (u16)0;
}

// ---------------- build x0 [n][320] bf16 (pad 0) + input_con output (f32)
__global__ __launch_bounds__(256)
void build_x0(const float* __restrict__ inp, const float* __restrict__ lat,
              u16* __restrict__ x0, float* __restrict__ con) {
  const int n = blockIdx.x;
  for (int i = threadIdx.x; i < 320; i += 256) {
    float v = (i < 3) ? inp[n * 3 + i] : ((i < 259) ? lat[i - 3] : 0.f);
    x0[(size_t)n * 320 + i] = f2bf(v);
    if (i < 259) con[(size_t)n * 259 + i] = v;
  }
}

// bijective XCD swizzle (grid % 8 == 0 by construction), m-major chunks:
// consecutive wg within an XCD chunk share the same n-tile (A reuse in L2).
__device__ __forceinline__ void xcd_decode(int nb, int ny, int& bx, int& by) {
  const int q = nb >> 3;
  const int wg = (blockIdx.x & 7) * q + (blockIdx.x >> 3);
  bx = wg / ny;
  by = wg - bx * ny;
}

// ---------------- fused MFMA layer: 1 wave / block, 64x64 tile, BK=32.
// A tile rows: mid = 4 streams x 16 points (stream == m-fragment);
//              first = 64 points. Per step the wave stages its own A(4KB)+B(4KB)
// via 8 global_load_lds into a private double buffer and paces on vmcnt(8) —
// NO barriers anywhere. LDS slot (row, c) holds k-chunk c ^ ((row>>1)&3);
// inverse permutation applied on the per-lane GLOBAL source address.
template<bool FIRST, int KPAD, int COUT, int CSTR>
__global__ __launch_bounds__(64)
void layer_mfma(const u16* __restrict__ W, const float* __restrict__ bias,
                const u16* __restrict__ Xin, u16* __restrict__ Xout, int ny) {
  constexpr int KSTEPS = KPAD / 32;
  __shared__ __align__(16) u16 smem[8192];   // 16 KB: 2 x (A 4KB + B 4KB)
  const int lane = threadIdx.x;              // 0..63
  const int lcol = lane & 15;
  const int hi = lane >> 4;                  // k-chunk 0..3 (8 bf16 each)
  const int lrow4 = hi * 4;

  int bx, by;
  xcd_decode(gridDim.x, ny, bx, by);
  const int n0 = bx * (FIRST ? 64 : 16);
  const int m0 = by * 64;

  f32x4 acc[4][4];
#pragma unroll
  for (int m = 0; m < 4; ++m)
#pragma unroll
    for (int n = 0; n < 4; ++n) acc[m][n] = (f32x4){0.f, 0.f, 0.f, 0.f};

  // staging: 8 GLDs/step (4 A + 4 B), each 16 rows x 64B.
  // lane -> row = lane>>2 (in 16-row group), slot = lane&3;
  // global chunk fetched = (lane&3) ^ ((row>>1)&3)   [inverse swizzle]
  const int ldiv = lane >> 2;
  const int kswz = ((lane & 3) ^ ((ldiv >> 1) & 3)) * 8;   // u16 units
  const u16* gA[4];
  const u16* gB[4];
#pragma unroll
  for (int i = 0; i < 4; ++i) {
    gA[i] = FIRST ? Xin + (size_t)(n0 + i * 16 + ldiv) * KPAD + kswz
                  : Xin + ((size_t)i * NPTS + n0 + ldiv) * KPAD + kswz;
    gB[i] = W + (size_t)(m0 + i * 16 + ldiv) * KPAD + kswz;
  }

  auto stage = [&](int ks, int bufu16) {     // compile-time args (unrolled loop)
    const int k0 = ks << 5;                  // bytes = 64*ks <= 1920, folds to imm
#pragma unroll
    for (int i = 0; i < 4; ++i) {
      GLD_LDS16(gA[i] + k0, smem + bufu16 + i * 512);
      GLD_LDS16(gB[i] + k0, smem + bufu16 + 2048 + i * 512);
    }
  };

  stage(0, 0);
  stage(1, 4096);
  // one vaddr for all 16 ds_reads; m/n/buffer become immediate offsets
  const int rdoff = lcol * 32 + (hi ^ ((lcol >> 1) & 3)) * 8;   // u16 units
#pragma unroll
  for (int ks = 0; ks < KSTEPS; ++ks) {
    if (ks + 1 < KSTEPS) {
      asm volatile("s_waitcnt vmcnt(8)" ::: "memory");   // own stage(ks) landed
    } else {
      asm volatile("s_waitcnt vmcnt(0)" ::: "memory");
    }
    const u16* buf = smem + (ks & 1) * 4096;
    bf16x8 af[4], bfr[4];
#pragma unroll
    for (int m = 0; m < 4; ++m)
      af[m] = *reinterpret_cast<const bf16x8*>(&buf[m * 512 + rdoff]);
#pragma unroll
    for (int n = 0; n < 4; ++n)
      bfr[n] = *reinterpret_cast<const bf16x8*>(&buf[2048 + n * 512 + rdoff]);
#pragma unroll
    for (int m = 0; m < 4; ++m)
#pragma unroll
      for (int n = 0; n < 4; ++n)
        acc[m][n] = __builtin_amdgcn_mfma_f32_16x16x32_bf16(af[m], bfr[n], acc[m][n], 0, 0, 0);
    if (ks + 2 < KSTEPS) {
      asm volatile("s_waitcnt lgkmcnt(0)" ::: "memory");  // own ds_reads drained
      stage(ks + 2, (ks & 1) * 4096);                     // overwrite own buffer
    }
  }

  // ---- epilogue: fully lane/register-local (1 wave, stream == m-fragment)
  if constexpr (!FIRST) {
#pragma unroll
    for (int n = 0; n < 4; ++n) {
      const int col = m0 + n * 16 + lcol;
      const bool ok = col < COUT;
      const float bcol = ok ? bias[col] : 0.f;
#pragma unroll
      for (int i = 0; i < 4; ++i) {
        const int p = lrow4 + i;                    // point 0..15
        float sp = 0.f, sg = 0.f;
        if (ok) act_sp_sg(acc[0][n][i] + bcol, sp, sg);
        const size_t base = (size_t)(n0 + p) * CSTR + col;
        Xout[base] = f2bf(sp);
        Xout[(size_t)1 * NPTS * CSTR + base] = f2bf(ok ? sg * acc[1][n][i] : 0.f);
        Xout[(size_t)2 * NPTS * CSTR + base] = f2bf(ok ? sg * acc[2][n][i] : 0.f);
        Xout[(size_t)3 * NPTS * CSTR + base] = f2bf(ok ? sg * acc[3][n][i] : 0.f);
      }
    }
  } else {
#pragma unroll
    for (int n = 0; n < 4; ++n) {
      const int col = m0 + n * 16 + lcol;
      const bool ok = col < COUT;
      float bcol = 0.f, w0 = 0.f, w1 = 0.f, w2 = 0.f;
      if (ok) {
        bcol = bias[col];
        w0 = bf2f(W[(size_t)col * KPAD + 0]);
        w1 = bf2f(W[(size_t)col * KPAD + 1]);
        w2 = bf2f(W[(size_t)col * KPAD + 2]);
      }
#pragma unroll
      for (int m = 0; m < 4; ++m)
#pragma unroll
        for (int i = 0; i < 4; ++i) {
          const int p = m * 16 + lrow4 + i;         // point 0..63
          float sp = 0.f, sg = 0.f;
          if (ok) act_sp_sg(acc[m][n][i] + bcol, sp, sg);
          const size_t base = (size_t)(n0 + p) * CSTR + col;
          Xout[base] = f2bf(sp);
          Xout[(size_t)1 * NPTS * CSTR + base] = f2bf(sg * w0);
          Xout[(size_t)2 * NPTS * CSTR + base] = f2bf(sg * w1);
          Xout[(size_t)3 * NPTS * CSTR + base] = f2bf(sg * w2);
        }
    }
  }
}

// ---------------- final 1-channel layer: out + out_grad
__global__ __launch_bounds__(256)
void final_c10(const u16* __restrict__ W10, const float* __restrict__ b10,
               const u16* __restrict__ Xin, float* __restrict__ out,
               float* __restrict__ outg) {
  const int lane = threadIdx.x & 63;
  const int n = blockIdx.x * 4 + (threadIdx.x >> 6);
  float a0 = 0, a1 = 0, a2 = 0, a3 = 0;
  for (int i = lane; i < 896; i += 64) {
    const float w = bf2f(W10[i]);
    a0 += w * bf2f(Xin[((size_t)0 * NPTS + n) * 896 + i]);
    a1 += w * bf2f(Xin[((size_t)1 * NPTS + n) * 896 + i]);
    a2 += w * bf2f(Xin[((size_t)2 * NPTS + n) * 896 + i]);
    a3 += w * bf2f(Xin[((size_t)3 * NPTS + n) * 896 + i]);
  }
#pragma unroll
  for (int off = 32; off > 0; off >>= 1) {
    a0 += __shfl_xor(a0, off); a1 += __shfl_xor(a1, off);
    a2 += __shfl_xor(a2, off); a3 += __shfl_xor(a3, off);
  }
  if (lane == 0) {
    out[n] = a0 + b10[0];
    outg[n * 3 + 0] = a1; outg[n * 3 + 1] = a2; outg[n * 3 + 2] = a3;
  }
}

template<int KPAD, int COUT, int CSTR>   // MPAD == CSTR for all layers here
static void launch_mid(const u16* W, const float* bias, const u16* Xi, u16* Xo,
                       hipStream_t stream) {
  const int ny = CSTR / 64;
  layer_mfma<false, KPAD, COUT, CSTR><<<dim3((NPTS / 16) * ny), dim3(64), 0, stream>>>(
      W, bias, Xi, Xo, ny);
}

extern "C" void kernel_launch(void* const* d_in, const int* in_sizes, int n_in,
                              void* d_out, int out_size, void* d_ws, size_t ws_size,
                              hipStream_t stream) {
  // K padded to 64-mult (legacy, fine for BK=32); MPAD = KPAD[l+1] (64-mult).
  static const int CIN  [12] = {259,515,512,512,576,576,768,768,768,960,960,896};
  static const int KPADA[12] = {320,576,512,512,576,576,768,768,768,960,960,896};
  static const int COUTA[12] = {515,512,512,576,576,768,768,768,960,960,896,1};
  static const int MPADA[12] = {576,512,512,576,576,768,768,768,960,960,896,1};

  size_t woff[13]; woff[0] = 0;
  for (int l = 0; l < 12; ++l) woff[l + 1] = woff[l] + (size_t)MPADA[l] * KPADA[l];

  char* ws = (char*)d_ws;
  u16* Wall = (u16*)ws;
  size_t off = (woff[12] * 2 + 255) & ~(size_t)255;
  u16* x0  = (u16*)(ws + off); off += (size_t)NPTS * 320 * 2;
  u16* XGA = (u16*)(ws + off); off += (size_t)4 * NPTS * 960 * 2;
  u16* XGB = (u16*)(ws + off);
  // total ws use ~72 MB

  float* out_sdf  = (float*)d_out;           // [4096]
  float* out_grad = out_sdf + NPTS;          // [4096][3]
  float* out_con  = out_sdf + NPTS + NPTS*3; // [4096][259]

  build_x0<<<dim3(NPTS), dim3(256), 0, stream>>>(
      (const float*)d_in[0], (const float*)d_in[1], x0, out_con);

  AllDesc ad;
  for (int l = 0; l < 12; ++l) {
    ad.d[l].v = (const float*)d_in[2 + 3 * l];
    ad.d[l].g = (const float*)d_in[3 + 3 * l];
    ad.d[l].Cin = CIN[l]; ad.d[l].Kpad = KPADA[l];
    ad.d[l].Cout = COUTA[l]; ad.d[l].Mpad = MPADA[l];
    ad.d[l].woff = (int)woff[l];
  }
  wnorm_kernel<<<dim3(960, 12), dim3(256), 0, stream>>>(ad, Wall);

  // layer 0 (first): x0 -> XGA; grid 64 n-blocks x 9 m-blocks = 576
  layer_mfma<true, 320, 515, 576><<<dim3((NPTS / 64) * 9), dim3(64), 0, stream>>>(
      Wall + woff[0], (const float*)d_in[4], x0, XGA, 9);

  // layers 1..10: ping-pong; tile rows = 4 streams x 16 points
  const float* b1  = (const float*)d_in[7];
  const float* b2  = (const float*)d_in[10];
  const float* b3  = (const float*)d_in[13];
  const float* b4  = (const float*)d_in[16];
  const float* b5  = (const float*)d_in[19];
  const float* b6  = (const float*)d_in[22];
  const float* b7  = (const float*)d_in[25];
  const float* b8  = (const float*)d_in[28];
  const float* b9  = (const float*)d_in[31];
  const float* b10 = (const float*)d_in[34];
  launch_mid<576, 512, 512>(Wall + woff[1],  b1,  XGA, XGB, stream);
  launch_mid<512, 512, 512>(Wall + woff[2],  b2,  XGB, XGA, stream);
  launch_mid<512, 576, 576>(Wall + woff[3],  b3,  XGA, XGB, stream);
  launch_mid<576, 576, 576>(Wall + woff[4],  b4,  XGB, XGA, stream);
  launch_mid<576, 768, 768>(Wall + woff[5],  b5,  XGA, XGB, stream);
  launch_mid<768, 768, 768>(Wall + woff[6],  b6,  XGB, XGA, stream);
  launch_mid<768, 768, 768>(Wall + woff[7],  b7,  XGA, XGB, stream);
  launch_mid<768, 960, 960>(Wall + woff[8],  b8,  XGB, XGA, stream);
  launch_mid<960, 960, 960>(Wall + woff[9],  b9,  XGA, XGB, stream);
  launch_mid<960, 896, 896>(Wall + woff[10], b10, XGB, XGA, stream);

  // final: layer 10 wrote XGA (stride 896)
  final_c10<<<dim3(NPTS / 4), dim3(256), 0, stream>>>(
      Wall + woff[11], (const float*)d_in[37], XGA, out_sdf, out_grad);
}

// Round 12
// 408.512 us; speedup vs baseline: 1.2029x; 1.2029x over previous
//
#include <hip/hip_runtime.h>
#include <hip/hip_bf16.h>

// Network_70918499991665: 12-layer implicit-map extractor, fwd + analytic grad.
// Round 11: r9 base (128x128, BK=32, 3x16KB rotating bufs, 1 barrier/step,
// counted vmcnt, unrolled templates) + T3-style fine phase interleave in the
// K-step: {reads -> lgkm fence -> dense 8-MFMA cluster} x2 with setprio(1)
// around each cluster and sched_barrier(0) fences (rule #18).

#define NPTS 4096

typedef unsigned short u16;
typedef unsigned int   u32;
typedef __attribute__((ext_vector_type(8))) __bf16 bf16x8;
typedef __attribute__((ext_vector_type(4))) float  f32x4;

#define GLD_LDS16(g, l) __builtin_amdgcn_global_load_lds(                  \
    (const __attribute__((address_space(1))) void*)(g),                   \
    (__attribute__((address_space(3))) void*)(l), 16, 0, 0)

__device__ __forceinline__ float bf2f(u16 h) {
  return __uint_as_float(((u32)h) << 16);
}
__device__ __forceinline__ u16 f2bf(float f) {
  u32 u = __float_as_uint(f);
  u += 0x7fff + ((u >> 16) & 1);   // RNE
  return (u16)(u >> 16);
}

// softplus(100x)/100 and sigmoid(100x), numerically stable
__device__ __forceinline__ void act_sp_sg(float pre, float& sp, float& sg) {
  float z = 100.f * pre;
  float e = __expf(-fabsf(z));
  float r = 1.f / (1.f + e);
  float l = __logf(1.f + e) * 0.01f;
  if (z >= 0.f) { sg = r;       sp = pre + l; }
  else          { sg = 1.f - r; sp = l; }
}

// ---------------- weight norm: w[o] = g[o]*v[o]/||v[o]||, store bf16, pad zeros
struct LayerDesc { const float* v; const float* g; int Cin, Kpad, Cout, Mpad, woff; };
struct AllDesc { LayerDesc d[12]; };

__global__ __launch_bounds__(256)
void wnorm_kernel(AllDesc ad, u16* __restrict__ Wall) {
  const LayerDesc L = ad.d[blockIdx.y];
  const int o = blockIdx.x;
  if (o >= L.Mpad) return;
  u16* wrow = Wall + (size_t)L.woff + (size_t)o * L.Kpad;
  const int t = threadIdx.x;
  if (o >= L.Cout) {                       // zero pad rows
    for (int i = t; i < L.Kpad; i += 256) wrow[i] = 0;
    return;
  }
  const float* vrow = L.v + (size_t)o * L.Cin;
  float ss = 0.f;
  for (int i = t; i < L.Cin; i += 256) { float x = vrow[i]; ss += x * x; }
#pragma unroll
  for (int off = 32; off > 0; off >>= 1) ss += __shfl_down(ss, off);
  __shared__ float red[4];
  if ((t & 63) == 0) red[t >> 6] = ss;
  __syncthreads();
  const float scale = L.g[o] / sqrtf(red[0] + red[1] + red[2] + red[3]);
  for (int i = t; i < L.Kpad; i += 256)
    wrow[i] = (i < L.Cin) ? f2bf(vrow[i] * scale) : (u16)0;
}

// ---------------- build x0 [n][320] bf16 (pad 0) + input_con output (f32)
__global__ __launch_bounds__(256)
void build_x0(const float* __restrict__ inp, const float* __restrict__ lat,
              u16* __restrict__ x0, float* __restrict__ con) {
  const int n = blockIdx.x;
  for (int i = threadIdx.x; i < 320; i += 256) {
    float v = (i < 3) ? inp[n * 3 + i] : ((i < 259) ? lat[i - 3] : 0.f);
    x0[(size_t)n * 320 + i] = f2bf(v);
    if (i < 259) con[(size_t)n * 259 + i] = v;
  }
}

// bijective XCD swizzle (grid % 8 == 0 by construction), m-major chunks
__device__ __forceinline__ void xcd_decode(int nb, int ny, int& bx, int& by) {
  const int q = nb >> 3;
  const int wg = (blockIdx.x & 7) * q + (blockIdx.x >> 3);
  bx = wg / ny;
  by = wg - bx * ny;
}

// ---------------- fused MFMA layer, 128x128 tile, BK=32, 4 waves.
// 3 rotating 16KB buffers (A 8KB + B 8KB), one barrier/step, counted vmcnt(4).
// LDS slot (row, c) holds global k-chunk c ^ ((row>>1)&3); inverse permutation
// on the per-lane GLOBAL address. K-loop fully unrolled; K-step body uses
// 2-phase cluster discipline: reads -> lgkm fence -> dense MFMA burst (x2).
template<bool FIRST, int KPAD, int COUT, int CSTR>
__global__ __launch_bounds__(256, 3)
void layer_mfma(const u16* __restrict__ W, const float* __restrict__ bias,
                const u16* __restrict__ Xin, u16* __restrict__ Xout, int ny) {
  constexpr int KSTEPS = KPAD / 32;
  __shared__ __align__(16) u16 smem[24576];   // 49,152 B: 3 x (A 8KB + B 8KB)
  const int t = threadIdx.x;
  const int wid = t >> 6, lane = t & 63;
  const int wr = wid >> 1, wc = wid & 1;
  const int lcol = lane & 15;
  const int hi = lane >> 4;                   // k-chunk 0..3 (8 bf16 each)
  const int lrow4 = hi * 4;

  int bx, by;
  xcd_decode(gridDim.x, ny, bx, by);
  const int n0 = bx * (FIRST ? 128 : 32);
  const int m0 = by * 128;

  f32x4 acc[4][4];
#pragma unroll
  for (int m = 0; m < 4; ++m)
#pragma unroll
    for (int n = 0; n < 4; ++n) acc[m][n] = (f32x4){0.f, 0.f, 0.f, 0.f};

  // staging: wave stages rows wid*32..+31 of A and B, 2 GLDs of 16 rows each.
  // lane -> row = lane>>2 (in 16-row group), slot = lane&3;
  // global chunk fetched = (lane&3) ^ ((row>>1)&3)   [inverse swizzle]
  const int ldiv = lane >> 2;
  const int kswz = ((lane & 3) ^ ((ldiv >> 1) & 3)) * 8;   // u16 units
  const u16* gA = FIRST
      ? Xin + (size_t)(n0 + wid * 32 + ldiv) * KPAD + kswz
      : Xin + ((size_t)wid * NPTS + n0 + ldiv) * KPAD + kswz;
  const u16* gB  = W + (size_t)(m0 + wid * 32 + ldiv) * KPAD + kswz;
  const u16* gA2 = gA + (size_t)16 * KPAD;
  const u16* gB2 = gB + (size_t)16 * KPAD;

  auto stage = [&](int ks, int bufu16) {     // ks, bufu16 compile-time (unrolled)
    const int k0 = ks << 5;                  // bytes = 64*ks <= 1920 -> imm offset
    GLD_LDS16(gA  + k0, smem + bufu16 + wid * 1024);
    GLD_LDS16(gA2 + k0, smem + bufu16 + wid * 1024 + 512);
    GLD_LDS16(gB  + k0, smem + bufu16 + 4096 + wid * 1024);
    GLD_LDS16(gB2 + k0, smem + bufu16 + 4096 + wid * 1024 + 512);
  };

  // per-lane ds_read offset (u16 units) within a 64-row half (A or B)
  const int rdswz = (hi ^ ((lcol >> 1) & 3)) * 8;   // same for all m,n rows:
  // row = base + m*16 + lcol -> (row>>1)&3 == (lcol>>1)&3 since base%64==0,16|m*16

  stage(0, 0);
  stage(1, 8192);
#pragma unroll
  for (int ks = 0; ks < KSTEPS; ++ks) {
    if (ks + 1 < KSTEPS) {
      asm volatile("s_waitcnt vmcnt(4)" ::: "memory");   // stage(ks) landed
    } else {
      asm volatile("s_waitcnt vmcnt(0)" ::: "memory");
    }
    __builtin_amdgcn_s_barrier();
    if (ks + 2 < KSTEPS) stage(ks + 2, ((ks + 2) % 3) * 8192);
    const u16* As = smem + (ks % 3) * 8192;  // static with full unroll
    const u16* Bs = As + 4096;
    // ---- phase reads: B0..B3, A0, A1 first; then A2, A3
    bf16x8 bfr[4], af[4];
#pragma unroll
    for (int n = 0; n < 4; ++n)
      bfr[n] = *reinterpret_cast<const bf16x8*>(
          &Bs[(wc * 64 + n * 16 + lcol) * 32 + rdswz]);
    af[0] = *reinterpret_cast<const bf16x8*>(&As[(wr * 64 +  0 + lcol) * 32 + rdswz]);
    af[1] = *reinterpret_cast<const bf16x8*>(&As[(wr * 64 + 16 + lcol) * 32 + rdswz]);
    af[2] = *reinterpret_cast<const bf16x8*>(&As[(wr * 64 + 32 + lcol) * 32 + rdswz]);
    af[3] = *reinterpret_cast<const bf16x8*>(&As[(wr * 64 + 48 + lcol) * 32 + rdswz]);
    // ---- cluster 1: m = 0,1 (needs bfr*, af0, af1 = first 6 reads)
    asm volatile("s_waitcnt lgkmcnt(2)" ::: "memory");
    __builtin_amdgcn_sched_barrier(0);
    __builtin_amdgcn_s_setprio(1);
#pragma unroll
    for (int m = 0; m < 2; ++m)
#pragma unroll
      for (int n = 0; n < 4; ++n)
        acc[m][n] = __builtin_amdgcn_mfma_f32_16x16x32_bf16(af[m], bfr[n], acc[m][n], 0, 0, 0);
    __builtin_amdgcn_s_setprio(0);
    // ---- cluster 2: m = 2,3
    asm volatile("s_waitcnt lgkmcnt(0)" ::: "memory");
    __builtin_amdgcn_sched_barrier(0);
    __builtin_amdgcn_s_setprio(1);
#pragma unroll
    for (int m = 2; m < 4; ++m)
#pragma unroll
      for (int n = 0; n < 4; ++n)
        acc[m][n] = __builtin_amdgcn_mfma_f32_16x16x32_bf16(af[m], bfr[n], acc[m][n], 0, 0, 0);
    __builtin_amdgcn_s_setprio(0);
  }
  __syncthreads();    // all waves done with buffers; smem free for epilogue

  if constexpr (!FIRST) {
    u16* tile = smem;                 // [64][144] u16 (18,432 B)
    u16* sgL  = smem + 64 * 144;      // [32][136] bf16 (8,704 B)

    if (wr == 0) {     // stream-0 rows (0..31): sg -> LDS(bf16), acc -> softplus
#pragma unroll
      for (int m = 0; m < 2; ++m)
#pragma unroll
        for (int n = 0; n < 4; ++n) {
          const int colL = wc * 64 + n * 16 + lcol;
          const int col = m0 + colL;
          const float bcol = (col < COUT) ? bias[col] : 0.f;
#pragma unroll
          for (int i = 0; i < 4; ++i) {
            const int p = m * 16 + lrow4 + i;
            float sp = 0.f, sg = 0.f;
            if (col < COUT) act_sp_sg(acc[m][n][i] + bcol, sp, sg);
            sgL[p * 136 + colL] = f2bf(sg);
            acc[m][n][i] = sp;
          }
        }
    }
    __syncthreads();

    auto store_half = [&](int sbase) {
#pragma unroll
      for (int j = 0; j < 4; ++j) {
        const int c = j * 256 + t;
        const int row = c >> 4, colc = c & 15;
        const int colg = m0 + colc * 8;
        if (colg < CSTR) {
          const int s = sbase + (row >> 5), p = row & 31;
          *reinterpret_cast<uint4*>(
              &Xout[((size_t)s * NPTS + n0 + p) * CSTR + colg]) =
              *reinterpret_cast<const uint4*>(&tile[row * 144 + colc * 8]);
        }
      }
    };

    // half A: rows 0..63 = streams 0,1 (owned by wr==0 waves)
    if (wr == 0) {
#pragma unroll
      for (int m = 0; m < 4; ++m)
#pragma unroll
        for (int n = 0; n < 4; ++n) {
          const int colL = wc * 64 + n * 16 + lcol;
#pragma unroll
          for (int i = 0; i < 4; ++i) {
            const int row = m * 16 + lrow4 + i;   // 0..63
            const float v = (row < 32) ? acc[m][n][i]
                                       : bf2f(sgL[(row & 31) * 136 + colL]) * acc[m][n][i];
            tile[row * 144 + colL] = f2bf(v);
          }
        }
    }
    __syncthreads();
    store_half(0);
    __syncthreads();
    // half B: rows 64..127 = streams 2,3 (owned by wr==1 waves)
    if (wr == 1) {
#pragma unroll
      for (int m = 0; m < 4; ++m)
#pragma unroll
        for (int n = 0; n < 4; ++n) {
          const int colL = wc * 64 + n * 16 + lcol;
#pragma unroll
          for (int i = 0; i < 4; ++i) {
            const int row = m * 16 + lrow4 + i;   // tile row 0..63
            const float v = bf2f(sgL[(row & 31) * 136 + colL]) * acc[m][n][i];
            tile[row * 144 + colL] = f2bf(v);
          }
        }
    }
    __syncthreads();
    store_half(2);
  } else {
    u16* tile = smem;                 // [128][144] u16 = 36,864 B
    float w0r[4], w1r[4], w2r[4], bcolr[4];
#pragma unroll
    for (int n = 0; n < 4; ++n) {
      const int col = m0 + wc * 64 + n * 16 + lcol;
      float b = 0.f, w0 = 0.f, w1 = 0.f, w2 = 0.f;
      if (col < COUT) {
        b  = bias[col];
        w0 = bf2f(W[(size_t)col * KPAD + 0]);
        w1 = bf2f(W[(size_t)col * KPAD + 1]);
        w2 = bf2f(W[(size_t)col * KPAD + 2]);
      }
      bcolr[n] = b; w0r[n] = w0; w1r[n] = w1; w2r[n] = w2;
    }
#pragma unroll
    for (int s = 0; s < 4; ++s) {
      if (s > 0) __syncthreads();
#pragma unroll
      for (int m = 0; m < 4; ++m)
#pragma unroll
        for (int n = 0; n < 4; ++n) {
          const int colL = wc * 64 + n * 16 + lcol;
          const bool ok = (m0 + colL) < COUT;
#pragma unroll
          for (int i = 0; i < 4; ++i) {
            const int row = wr * 64 + m * 16 + lrow4 + i;
            float v = 0.f;
            if (ok) {
              float sp, sg;
              act_sp_sg(acc[m][n][i] + bcolr[n], sp, sg);
              v = (s == 0) ? sp
                : (s == 1) ? sg * w0r[n]
                : (s == 2) ? sg * w1r[n]
                           : sg * w2r[n];
            }
            tile[row * 144 + colL] = f2bf(v);
          }
        }
      __syncthreads();
#pragma unroll
      for (int j = 0; j < 8; ++j) {
        const int c = j * 256 + t;
        const int row = c >> 4, colc = c & 15;
        const int colg = m0 + colc * 8;
        if (colg < CSTR) {
          *reinterpret_cast<uint4*>(
              &Xout[((size_t)s * NPTS + n0 + row) * CSTR + colg]) =
              *reinterpret_cast<const uint4*>(&tile[row * 144 + colc * 8]);
        }
      }
    }
  }
}

// ---------------- final 1-channel layer: out + out_grad
__global__ __launch_bounds__(256)
void final_c10(const u16* __restrict__ W10, const float* __restrict__ b10,
               const u16* __restrict__ Xin, float* __restrict__ out,
               float* __restrict__ outg) {
  const int lane = threadIdx.x & 63;
  const int n = blockIdx.x * 4 + (threadIdx.x >> 6);
  float a0 = 0, a1 = 0, a2 = 0, a3 = 0;
  for (int i = lane; i < 896; i += 64) {
    const float w = bf2f(W10[i]);
    a0 += w * bf2f(Xin[((size_t)0 * NPTS + n) * 896 + i]);
    a1 += w * bf2f(Xin[((size_t)1 * NPTS + n) * 896 + i]);
    a2 += w * bf2f(Xin[((size_t)2 * NPTS + n) * 896 + i]);
    a3 += w * bf2f(Xin[((size_t)3 * NPTS + n) * 896 + i]);
  }
#pragma unroll
  for (int off = 32; off > 0; off >>= 1) {
    a0 += __shfl_xor(a0, off); a1 += __shfl_xor(a1, off);
    a2 += __shfl_xor(a2, off); a3 += __shfl_xor(a3, off);
  }
  if (lane == 0) {
    out[n] = a0 + b10[0];
    outg[n * 3 + 0] = a1; outg[n * 3 + 1] = a2; outg[n * 3 + 2] = a3;
  }
}

template<int KPAD, int COUT, int CSTR>
static void launch_mid(const u16* W, const float* bias, const u16* Xi, u16* Xo,
                       int mpad, hipStream_t stream) {
  const int ny = mpad / 128;
  layer_mfma<false, KPAD, COUT, CSTR><<<dim3((NPTS / 32) * ny), dim3(256), 0, stream>>>(
      W, bias, Xi, Xo, ny);
}

extern "C" void kernel_launch(void* const* d_in, const int* in_sizes, int n_in,
                              void* d_out, int out_size, void* d_ws, size_t ws_size,
                              hipStream_t stream) {
  // K padded to 32-mult; Cout padded to 128-mult (MPAD).
  static const int CIN  [12] = {259,515,512,512,576,576,768,768,768,960,960,896};
  static const int KPADA[12] = {320,576,512,512,576,576,768,768,768,960,960,896};
  static const int COUTA[12] = {515,512,512,576,576,768,768,768,960,960,896,1};
  static const int MPADA[12] = {640,512,512,640,640,768,768,768,1024,1024,896,1};

  size_t woff[13]; woff[0] = 0;
  for (int l = 0; l < 12; ++l) woff[l + 1] = woff[l] + (size_t)MPADA[l] * KPADA[l];

  char* ws = (char*)d_ws;
  u16* Wall = (u16*)ws;
  size_t off = (woff[12] * 2 + 255) & ~(size_t)255;
  u16* x0  = (u16*)(ws + off); off += (size_t)NPTS * 320 * 2;
  u16* XGA = (u16*)(ws + off); off += (size_t)4 * NPTS * 960 * 2;
  u16* XGB = (u16*)(ws + off);
  // total ws use ~77 MB

  float* out_sdf  = (float*)d_out;           // [4096]
  float* out_grad = out_sdf + NPTS;          // [4096][3]
  float* out_con  = out_sdf + NPTS + NPTS*3; // [4096][259]

  build_x0<<<dim3(NPTS), dim3(256), 0, stream>>>(
      (const float*)d_in[0], (const float*)d_in[1], x0, out_con);

  AllDesc ad;
  for (int l = 0; l < 12; ++l) {
    ad.d[l].v = (const float*)d_in[2 + 3 * l];
    ad.d[l].g = (const float*)d_in[3 + 3 * l];
    ad.d[l].Cin = CIN[l]; ad.d[l].Kpad = KPADA[l];
    ad.d[l].Cout = COUTA[l]; ad.d[l].Mpad = MPADA[l];
    ad.d[l].woff = (int)woff[l];
  }
  wnorm_kernel<<<dim3(1024, 12), dim3(256), 0, stream>>>(ad, Wall);

  // layer 0 (first): x0 -> XGA (out stride 576); grid 32 x 5 = 160 blocks
  layer_mfma<true, 320, 515, 576><<<dim3((NPTS / 128) * 5), dim3(256), 0, stream>>>(
      Wall + woff[0], (const float*)d_in[4], x0, XGA, 5);

  // layers 1..10: ping-pong; tile rows = 4 streams x 32 points
  const float* b1  = (const float*)d_in[7];
  const float* b2  = (const float*)d_in[10];
  const float* b3  = (const float*)d_in[13];
  const float* b4  = (const float*)d_in[16];
  const float* b5  = (const float*)d_in[19];
  const float* b6  = (const float*)d_in[22];
  const float* b7  = (const float*)d_in[25];
  const float* b8  = (const float*)d_in[28];
  const float* b9  = (const float*)d_in[31];
  const float* b10 = (const float*)d_in[34];
  launch_mid<576, 512, 512>(Wall + woff[1],  b1,  XGA, XGB, MPADA[1],  stream);
  launch_mid<512, 512, 512>(Wall + woff[2],  b2,  XGB, XGA, MPADA[2],  stream);
  launch_mid<512, 576, 576>(Wall + woff[3],  b3,  XGA, XGB, MPADA[3],  stream);
  launch_mid<576, 576, 576>(Wall + woff[4],  b4,  XGB, XGA, MPADA[4],  stream);
  launch_mid<576, 768, 768>(Wall + woff[5],  b5,  XGA, XGB, MPADA[5],  stream);
  launch_mid<768, 768, 768>(Wall + woff[6],  b6,  XGB, XGA, MPADA[6],  stream);
  launch_mid<768, 768, 768>(Wall + woff[7],  b7,  XGA, XGB, MPADA[7],  stream);
  launch_mid<768, 960, 960>(Wall + woff[8],  b8,  XGB, XGA, MPADA[8],  stream);
  launch_mid<960, 960, 960>(Wall + woff[9],  b9,  XGA, XGB, MPADA[9],  stream);
  launch_mid<960, 896, 896>(Wall + woff[10], b10, XGB, XGA, MPADA[10], stream);

  // final: layer 10 wrote XGA (stride 896)
  final_c10<<<dim3(NPTS / 4), dim3(256), 0, stream>>>(
      Wall + woff[11], (const float*)d_in[37], XGA, out_sdf, out_grad);
}

// Round 13
// 225.878 us; speedup vs baseline: 2.1754x; 1.8085x over previous
//
#include <hip/hip_runtime.h>
#include <hip/hip_bf16.h>

// Network_70918499991665: 12-layer implicit-map extractor, fwd + analytic grad.
// Round 12: FULLY FUSED pointwise network. The op is a 1x1-conv chain: each
// point's 12-layer pipeline is independent. One kernel, 256 blocks x 768 thr,
// 16 points/block; activations (64 rows x <=960 cols bf16) live in LDS across
// all layers (zero intermediate HBM). Weights pre-packed in MFMA-fragment
// order -> per-wave 1KB contiguous loads, L2-broadcast. Sigmoid coupling is
// exactly register-local (stream s == same lane/reg as stream 0).

#define NPTS 4096
#define XS 968          // X LDS row stride in u16 (pad: 484 dwords % 32 = 4)

typedef unsigned short u16;
typedef unsigned int   u32;
typedef __attribute__((ext_vector_type(8))) __bf16 bf16x8;
typedef __attribute__((ext_vector_type(4))) float  f32x4;

__device__ __forceinline__ float bf2f(u16 h) {
  return __uint_as_float(((u32)h) << 16);
}
__device__ __forceinline__ u16 f2bf(float f) {
  u32 u = __float_as_uint(f);
  u += 0x7fff + ((u >> 16) & 1);   // RNE
  return (u16)(u >> 16);
}

// softplus(100x)/100 and sigmoid(100x), numerically stable
__device__ __forceinline__ void act_sp_sg(float pre, float& sp, float& sg) {
  float z = 100.f * pre;
  float e = __expf(-fabsf(z));
  float r = 1.f / (1.f + e);
  float l = __logf(1.f + e) * 0.01f;
  if (z >= 0.f) { sg = r;       sp = pre + l; }
  else          { sg = 1.f - r; sp = l; }
}

// ---------------- build x0 [n][320] bf16 (pad 0) + input_con output (f32)
__global__ __launch_bounds__(256)
void build_x0(const float* __restrict__ inp, const float* __restrict__ lat,
              u16* __restrict__ x0, float* __restrict__ con) {
  const int n = blockIdx.x;
  for (int i = threadIdx.x; i < 320; i += 256) {
    float v = (i < 3) ? inp[n * 3 + i] : ((i < 259) ? lat[i - 3] : 0.f);
    x0[(size_t)n * 320 + i] = f2bf(v);
    if (i < 259) con[(size_t)n * 259 + i] = v;
  }
}

// ---------------- weight-norm + pack into MFMA B-fragment order.
// Element (col,k) of layer weight -> frag (cb=col/16, ks=k/32), lane =
// (col&15) + ((k>>3)&3)*16, byte j = k&7. Frag storage: [ks][cb] major:
// u16 offset = (ks*MF + cb)*512 + lane*8 + j. Writes are fully coalesced u32.
struct WLayer { const float* v; const float* g; int Cin, Cout, KS, MF; size_t woff; };
struct WAll { WLayer L[11]; };

__global__ __launch_bounds__(256)
void wnormF(WAll wa, u16* __restrict__ Wf) {
  const WLayer L = wa.L[blockIdx.y];
  const int cb = blockIdx.x;
  if (cb >= L.MF) return;
  __shared__ float red[16][17];
  __shared__ float scl[16];
  const int t = threadIdx.x;
  {
    const int col16 = t & 15, kt = t >> 4;
    const int col = cb * 16 + col16;
    float ss = 0.f;
    if (col < L.Cout)
      for (int k = kt; k < L.Cin; k += 16) {
        float x = L.v[(size_t)col * L.Cin + k]; ss += x * x;
      }
    red[col16][kt] = ss;
  }
  __syncthreads();
  if (t < 16) {
    float s = 0.f;
#pragma unroll
    for (int j = 0; j < 16; ++j) s += red[t][j];
    const int c = cb * 16 + t;
    scl[t] = (c < L.Cout) ? L.g[c] / sqrtf(s) : 0.f;
  }
  __syncthreads();
  u32* dst = (u32*)(Wf + L.woff);
  const int lane = t >> 2, q = t & 3;
  const int vcol = cb * 16 + (lane & 15);
  const float sc = scl[lane & 15];
  const float* vrow = L.v + (size_t)vcol * L.Cin;
  const bool cok = vcol < L.Cout;
  for (int ks = 0; ks < L.KS; ++ks) {
    const int k0 = ks * 32 + (lane >> 4) * 8 + q * 2;
    u16 lo = 0, hi16 = 0;
    if (cok) {
      if (k0 < L.Cin)     lo   = f2bf(vrow[k0] * sc);
      if (k0 + 1 < L.Cin) hi16 = f2bf(vrow[k0 + 1] * sc);
    }
    dst[(size_t)(ks * L.MF + cb) * 128 + t] = (u32)lo | ((u32)hi16 << 16);
  }
}

// ---------------- fused network ----------------
struct FusedArgs {
  size_t woff[11];
  const float* bias[11];
  const float* v10; const float* g10; const float* b10;
};

// Mid layer: X rows 0..63 = 4 streams x 16 points, cols [0,KS*32) in.
// Out: cols [0, MF*16) written back into X (after barrier).
template<int KS, int MF, int COUT>
__device__ __forceinline__ void layer_mid(const u16* __restrict__ Wf,
                                          const float* __restrict__ bias,
                                          u16* __restrict__ X,
                                          int w, int lane, int lcol, int hi) {
  constexpr int NF = (MF + 11) / 12;
  f32x4 acc[4][NF];
#pragma unroll
  for (int s = 0; s < 4; ++s)
#pragma unroll
    for (int i = 0; i < NF; ++i) acc[s][i] = (f32x4){0.f, 0.f, 0.f, 0.f};

  const u16* wp = Wf + lane * 8;
  const int abase = lcol * XS + hi * 8;
  bf16x8 bA[NF], bB[NF];
#pragma unroll
  for (int i = 0; i < NF; ++i)
    if (w + 12 * i < MF)
      bA[i] = *(const bf16x8*)(wp + (size_t)(w + 12 * i) * 512);

#pragma unroll 1
  for (int ks = 0; ks < KS; ks += 2) {
    bf16x8 af[4];
#pragma unroll
    for (int s = 0; s < 4; ++s)
      af[s] = *(const bf16x8*)(X + abase + s * 16 * XS + ks * 32);
#pragma unroll
    for (int i = 0; i < NF; ++i)
      if (w + 12 * i < MF)
        bB[i] = *(const bf16x8*)(wp + (size_t)((ks + 1) * MF + w + 12 * i) * 512);
#pragma unroll
    for (int i = 0; i < NF; ++i)
      if (w + 12 * i < MF)
#pragma unroll
        for (int s = 0; s < 4; ++s)
          acc[s][i] = __builtin_amdgcn_mfma_f32_16x16x32_bf16(af[s], bA[i], acc[s][i], 0, 0, 0);
#pragma unroll
    for (int s = 0; s < 4; ++s)
      af[s] = *(const bf16x8*)(X + abase + s * 16 * XS + ks * 32 + 32);
    if (ks + 2 < KS) {
#pragma unroll
      for (int i = 0; i < NF; ++i)
        if (w + 12 * i < MF)
          bA[i] = *(const bf16x8*)(wp + (size_t)((ks + 2) * MF + w + 12 * i) * 512);
    }
#pragma unroll
    for (int i = 0; i < NF; ++i)
      if (w + 12 * i < MF)
#pragma unroll
        for (int s = 0; s < 4; ++s)
          acc[s][i] = __builtin_amdgcn_mfma_f32_16x16x32_bf16(af[s], bB[i], acc[s][i], 0, 0, 0);
  }
  __syncthreads();   // all waves done reading X_in
  // epilogue: register-local sigmoid coupling; write X_out
#pragma unroll
  for (int i = 0; i < NF; ++i) {
    const int cb = w + 12 * i;
    if (cb < MF) {
      const int col = cb * 16 + lcol;
      const bool ok = col < COUT;
      const float bc = ok ? bias[col] : 0.f;
#pragma unroll
      for (int r = 0; r < 4; ++r) {
        const int p = hi * 4 + r;
        float sp = 0.f, sg = 0.f;
        if (ok) act_sp_sg(acc[0][i][r] + bc, sp, sg);
        X[(0 * 16 + p) * XS + col] = f2bf(sp);
        X[(1 * 16 + p) * XS + col] = f2bf(ok ? sg * acc[1][i][r] : 0.f);
        X[(2 * 16 + p) * XS + col] = f2bf(ok ? sg * acc[2][i][r] : 0.f);
        X[(3 * 16 + p) * XS + col] = f2bf(ok ? sg * acc[3][i][r] : 0.f);
      }
    }
  }
  __syncthreads();
}

// First layer: X rows 0..15 = 16 points x Cin; grads from W[:, :3].
template<int KS, int MF, int COUT>
__device__ __forceinline__ void layer_first(const u16* __restrict__ Wf,
                                            const float* __restrict__ bias,
                                            u16* __restrict__ X,
                                            int w, int lane, int lcol, int hi) {
  constexpr int NF = (MF + 11) / 12;
  f32x4 acc[NF];
#pragma unroll
  for (int i = 0; i < NF; ++i) acc[i] = (f32x4){0.f, 0.f, 0.f, 0.f};
  const u16* wp = Wf + lane * 8;
  const int abase = lcol * XS + hi * 8;
  bf16x8 bA[NF], bB[NF];
#pragma unroll
  for (int i = 0; i < NF; ++i)
    if (w + 12 * i < MF)
      bA[i] = *(const bf16x8*)(wp + (size_t)(w + 12 * i) * 512);
#pragma unroll 1
  for (int ks = 0; ks < KS; ks += 2) {
    bf16x8 af0 = *(const bf16x8*)(X + abase + ks * 32);
#pragma unroll
    for (int i = 0; i < NF; ++i)
      if (w + 12 * i < MF)
        bB[i] = *(const bf16x8*)(wp + (size_t)((ks + 1) * MF + w + 12 * i) * 512);
#pragma unroll
    for (int i = 0; i < NF; ++i)
      if (w + 12 * i < MF)
        acc[i] = __builtin_amdgcn_mfma_f32_16x16x32_bf16(af0, bA[i], acc[i], 0, 0, 0);
    bf16x8 af1 = *(const bf16x8*)(X + abase + ks * 32 + 32);
    if (ks + 2 < KS) {
#pragma unroll
      for (int i = 0; i < NF; ++i)
        if (w + 12 * i < MF)
          bA[i] = *(const bf16x8*)(wp + (size_t)((ks + 2) * MF + w + 12 * i) * 512);
    }
#pragma unroll
    for (int i = 0; i < NF; ++i)
      if (w + 12 * i < MF)
        acc[i] = __builtin_amdgcn_mfma_f32_16x16x32_bf16(af1, bB[i], acc[i], 0, 0, 0);
  }
  __syncthreads();
#pragma unroll
  for (int i = 0; i < NF; ++i) {
    const int cb = w + 12 * i;
    if (cb < MF) {
      const int col = cb * 16 + lcol;
      const bool ok = col < COUT;
      float bc = 0.f, w0 = 0.f, w1 = 0.f, w2 = 0.f;
      if (ok) {
        bc = bias[col];
        const u16* wk = Wf + ((size_t)cb * 64 + lcol) * 8;  // frag ks=0
        w0 = bf2f(wk[0]); w1 = bf2f(wk[1]); w2 = bf2f(wk[2]);
      }
#pragma unroll
      for (int r = 0; r < 4; ++r) {
        const int p = hi * 4 + r;
        float sp = 0.f, sg = 0.f;
        if (ok) act_sp_sg(acc[i][r] + bc, sp, sg);
        X[(0 * 16 + p) * XS + col] = f2bf(sp);
        X[(1 * 16 + p) * XS + col] = f2bf(sg * w0);
        X[(2 * 16 + p) * XS + col] = f2bf(sg * w1);
        X[(3 * 16 + p) * XS + col] = f2bf(sg * w2);
      }
    }
  }
  __syncthreads();
}

__global__ __launch_bounds__(768, 1)
void fused_net(FusedArgs fa, const u16* __restrict__ WfAll,
               const u16* __restrict__ x0,
               float* __restrict__ out, float* __restrict__ outg) {
  __shared__ __align__(16) u16 X[64 * XS];
  __shared__ float fred[12];
  const int t = threadIdx.x;
  const int w = t >> 6, lane = t & 63;
  const int lcol = lane & 15, hi = lane >> 4;
  const int n0 = blockIdx.x * 16;

  // stage x0: 16 rows x 320 u16 (40 x 16B chunks per row)
  for (int c = t; c < 640; c += 768) {
    const int row = c / 40, ch = c % 40;
    uint4 q = *reinterpret_cast<const uint4*>(x0 + (size_t)(n0 + row) * 320 + ch * 8);
    *reinterpret_cast<uint4*>(X + row * XS + ch * 8) = q;
  }
  __syncthreads();

  layer_first<10, 36, 515>(WfAll + fa.woff[0],  fa.bias[0],  X, w, lane, lcol, hi);
  layer_mid<18, 32, 512>(WfAll + fa.woff[1],  fa.bias[1],  X, w, lane, lcol, hi);
  layer_mid<16, 32, 512>(WfAll + fa.woff[2],  fa.bias[2],  X, w, lane, lcol, hi);
  layer_mid<16, 36, 576>(WfAll + fa.woff[3],  fa.bias[3],  X, w, lane, lcol, hi);
  layer_mid<18, 36, 576>(WfAll + fa.woff[4],  fa.bias[4],  X, w, lane, lcol, hi);
  layer_mid<18, 48, 768>(WfAll + fa.woff[5],  fa.bias[5],  X, w, lane, lcol, hi);
  layer_mid<24, 48, 768>(WfAll + fa.woff[6],  fa.bias[6],  X, w, lane, lcol, hi);
  layer_mid<24, 48, 768>(WfAll + fa.woff[7],  fa.bias[7],  X, w, lane, lcol, hi);
  layer_mid<24, 60, 960>(WfAll + fa.woff[8],  fa.bias[8],  X, w, lane, lcol, hi);
  layer_mid<30, 60, 960>(WfAll + fa.woff[9],  fa.bias[9],  X, w, lane, lcol, hi);
  layer_mid<30, 56, 896>(WfAll + fa.woff[10], fa.bias[10], X, w, lane, lcol, hi);

  // final c10: weight-norm inline + 64 dots of length 896
  float ss = 0.f;
  for (int k = t; k < 896; k += 768) { float x = fa.v10[k]; ss += x * x; }
#pragma unroll
  for (int off = 32; off > 0; off >>= 1) ss += __shfl_xor(ss, off);
  if (lane == 0) fred[w] = ss;
  __syncthreads();
  float tot = 0.f;
#pragma unroll
  for (int j = 0; j < 12; ++j) tot += fred[j];
  const float scale = fa.g10[0] / sqrtf(tot);

  for (int id = w; id < 64; id += 12) {
    const int s = id >> 4, p = id & 15;
    const u16* xr = X + (s * 16 + p) * XS;
    float d = 0.f;
#pragma unroll
    for (int j = 0; j < 14; ++j) {
      const int k = lane * 14 + j;
      d += fa.v10[k] * bf2f(xr[k]);
    }
    d *= scale;
#pragma unroll
    for (int off = 32; off > 0; off >>= 1) d += __shfl_xor(d, off);
    if (lane == 0) {
      if (s == 0) out[n0 + p] = d + fa.b10[0];
      else        outg[(size_t)(n0 + p) * 3 + (s - 1)] = d;
    }
  }
}

extern "C" void kernel_launch(void* const* d_in, const int* in_sizes, int n_in,
                              void* d_out, int out_size, void* d_ws, size_t ws_size,
                              hipStream_t stream) {
  static const int CIN [11] = {259,515,512,512,576,576,768,768,768,960,960};
  static const int COUT[11] = {515,512,512,576,576,768,768,768,960,960,896};
  static const int KS  [11] = {10,18,16,16,18,18,24,24,24,30,30};
  static const int MF  [11] = {36,32,32,36,36,48,48,48,60,60,56};

  size_t woff[12]; woff[0] = 0;
  for (int l = 0; l < 11; ++l)
    woff[l + 1] = woff[l] + (size_t)KS[l] * MF[l] * 512;

  char* ws = (char*)d_ws;
  u16* Wf = (u16*)ws;
  size_t off = (woff[11] * 2 + 255) & ~(size_t)255;
  u16* x0 = (u16*)(ws + off);
  // ws use: ~11 MB Wf + 2.6 MB x0

  float* out_sdf  = (float*)d_out;           // [4096]
  float* out_grad = out_sdf + NPTS;          // [4096][3]
  float* out_con  = out_sdf + NPTS + NPTS*3; // [4096][259]

  build_x0<<<dim3(NPTS), dim3(256), 0, stream>>>(
      (const float*)d_in[0], (const float*)d_in[1], x0, out_con);

  WAll wa;
  for (int l = 0; l < 11; ++l) {
    wa.L[l].v = (const float*)d_in[2 + 3 * l];
    wa.L[l].g = (const float*)d_in[3 + 3 * l];
    wa.L[l].Cin = CIN[l]; wa.L[l].Cout = COUT[l];
    wa.L[l].KS = KS[l]; wa.L[l].MF = MF[l];
    wa.L[l].woff = woff[l];
  }
  wnormF<<<dim3(60, 11), dim3(256), 0, stream>>>(wa, Wf);

  FusedArgs fa;
  for (int l = 0; l < 11; ++l) {
    fa.woff[l] = woff[l];
    fa.bias[l] = (const float*)d_in[4 + 3 * l];
  }
  fa.v10 = (const float*)d_in[35];
  fa.g10 = (const float*)d_in[36];
  fa.b10 = (const float*)d_in[37];

  fused_net<<<dim3(NPTS / 16), dim3(768), 0, stream>>>(
      fa, Wf, x0, out_sdf, out_grad);
}